// Round 1
// baseline (401.834 us; speedup 1.0000x reference)
//
#include <hip/hip_runtime.h>
#include <math.h>

#define NUM_CLASSES 26
#define HH 512
#define WW 512
#define NB 4
#define PHH 171
#define PWW 171
#define NHH 169
#define NWW 169
#define MPTS (NHH*NWW)        // 28561
#define NCT (NB*NUM_CLASSES)  // 104
#define CLIPV 1e-6f

// ---------------- Kernel 1: fused mask/sigmoid + 3x3 stride-3 maxpool (pad 1, -inf) ----------
__global__ void pool_kernel(const float* __restrict__ cls, const float* __restrict__ tgt,
                            const float* __restrict__ mask,
                            float* __restrict__ poolL, float* __restrict__ poolP) {
    int idx = blockIdx.x * blockDim.x + threadIdx.x;
    const int total = NCT * PHH * PWW;
    if (idx >= total) return;
    int pw = idx % PWW;
    int t  = idx / PWW;
    int ph = t % PHH;
    int nc = t / PHH;
    int n  = nc / NUM_CLASSES;

    const float* clsBase = cls + (size_t)nc * HH * WW;
    const float* tgtBase = tgt + (size_t)nc * HH * WW;
    const float* mBase   = mask + (size_t)n  * HH * WW;

    float maxL = -INFINITY, maxP = -INFINITY;
    int r0 = 3*ph - 1, c0 = 3*pw - 1;
    #pragma unroll
    for (int dr = 0; dr < 3; ++dr) {
        int r = r0 + dr;
        if (r < 0 || r >= HH) continue;
        #pragma unroll
        for (int dc = 0; dc < 3; ++dc) {
            int c = c0 + dc;
            if (c < 0 || c >= WW) continue;
            size_t off = (size_t)r * WW + c;
            float m  = mBase[off];
            float lv = tgtBase[off] * m;
            float x  = clsBase[off];
            float sg = __fdividef(1.0f, 1.0f + __expf(-x));
            float pv = sg * m + CLIPV;
            maxL = fmaxf(maxL, lv);
            maxP = fmaxf(maxP, pv);
        }
    }
    poolL[idx] = maxL;
    poolP[idx] = maxP;
}

// ---------------- Kernel 2: covariance raw-sum accumulation ----------------
// blockIdx.x = nc (0..103), blockIdx.y = mode: 0 = L*L (45)+sumL(9), 1 = P*P (45)+sumP(9), 2 = L*P (81)
__global__ void cov_kernel(const float* __restrict__ poolL, const float* __restrict__ poolP,
                           float* __restrict__ covL, float* __restrict__ covP,
                           float* __restrict__ covLP, float* __restrict__ sumL,
                           float* __restrict__ sumP) {
    int nc = blockIdx.x;
    int mode = blockIdx.y;
    int tid = threadIdx.x;
    const float* Lb = poolL + (size_t)nc * PHH * PWW;
    const float* Pb = poolP + (size_t)nc * PHH * PWW;

    __shared__ float red[4][81];
    int wave = tid >> 6, lane = tid & 63;

    if (mode < 2) {
        const float* src = (mode == 0) ? Lb : Pb;
        float acc[45];
        float s[9];
        #pragma unroll
        for (int k = 0; k < 45; ++k) acc[k] = 0.f;
        #pragma unroll
        for (int k = 0; k < 9; ++k) s[k] = 0.f;

        for (int p = tid; p < MPTS; p += blockDim.x) {
            int i = p / NWW, j = p - i * NWW;
            float v[9];
            #pragma unroll
            for (int dy = 0; dy < 3; ++dy)
                #pragma unroll
                for (int dx = 0; dx < 3; ++dx)
                    v[dy*3+dx] = src[(i+dy)*PWW + (j+dx)];
            #pragma unroll
            for (int d = 0; d < 9; ++d) s[d] += v[d];
            int k = 0;
            #pragma unroll
            for (int d = 0; d < 9; ++d)
                #pragma unroll
                for (int e = d; e < 9; ++e)
                    acc[k++] += v[d] * v[e];
        }
        // reduce 45 products
        #pragma unroll
        for (int k = 0; k < 45; ++k) {
            float x = acc[k];
            #pragma unroll
            for (int off = 32; off > 0; off >>= 1) x += __shfl_down(x, off);
            if (lane == 0) red[wave][k] = x;
        }
        #pragma unroll
        for (int k = 0; k < 9; ++k) {
            float x = s[k];
            #pragma unroll
            for (int off = 32; off > 0; off >>= 1) x += __shfl_down(x, off);
            if (lane == 0) red[wave][45+k] = x;
        }
        __syncthreads();
        if (tid < 54) {
            float x = red[0][tid] + red[1][tid] + red[2][tid] + red[3][tid];
            if (tid < 45) {
                ((mode == 0) ? covL : covP)[nc*45 + tid] = x;
            } else {
                ((mode == 0) ? sumL : sumP)[nc*9 + (tid - 45)] = x;
            }
        }
    } else {
        float acc[81];
        #pragma unroll
        for (int k = 0; k < 81; ++k) acc[k] = 0.f;
        for (int p = tid; p < MPTS; p += blockDim.x) {
            int i = p / NWW, j = p - i * NWW;
            float vl[9], vp[9];
            #pragma unroll
            for (int dy = 0; dy < 3; ++dy)
                #pragma unroll
                for (int dx = 0; dx < 3; ++dx) {
                    vl[dy*3+dx] = Lb[(i+dy)*PWW + (j+dx)];
                    vp[dy*3+dx] = Pb[(i+dy)*PWW + (j+dx)];
                }
            #pragma unroll
            for (int d = 0; d < 9; ++d)
                #pragma unroll
                for (int e = 0; e < 9; ++e)
                    acc[d*9+e] += vl[d] * vp[e];
        }
        #pragma unroll
        for (int k = 0; k < 81; ++k) {
            float x = acc[k];
            #pragma unroll
            for (int off = 32; off > 0; off >>= 1) x += __shfl_down(x, off);
            if (lane == 0) red[wave][k] = x;
        }
        __syncthreads();
        if (tid < 81) {
            covLP[nc*81 + tid] = red[0][tid] + red[1][tid] + red[2][tid] + red[3][tid];
        }
    }
}

// ---------------- Kernel 3: per-(n,c) 9x9 algebra + global reduction ----------------
__global__ void solve_kernel(const float* __restrict__ covL, const float* __restrict__ covP,
                             const float* __restrict__ covLP, const float* __restrict__ sumL,
                             const float* __restrict__ sumP, float* __restrict__ out) {
    int t = threadIdx.x;
    double r = 0.0;
    if (t < NCT) {
        const double M = (double)MPTS;
        double All[9][9], C[9][9], Pm[9][9];
        double sL[9], sP[9];
        for (int d = 0; d < 9; ++d) { sL[d] = sumL[t*9+d]; sP[d] = sumP[t*9+d]; }
        {
            int k = 0;
            for (int d = 0; d < 9; ++d)
                for (int e = d; e < 9; ++e) {
                    double v = (double)covL[t*45+k] - sL[d]*sL[e]/M;
                    All[d][e] = v; All[e][d] = v;
                    double w = (double)covP[t*45+k] - sP[d]*sP[e]/M;
                    C[d][e] = w; C[e][d] = w;
                    ++k;
                }
            for (int d = 0; d < 9; ++d)
                for (int e = 0; e < 9; ++e)
                    Pm[d][e] = (double)covLP[t*81 + d*9+e] - sL[d]*sP[e]/M;
            for (int d = 0; d < 9; ++d) C[d][d] += 1e-3;
        }
        // Cholesky of C (pr_cov + alpha I), in place -> lower G
        for (int i = 0; i < 9; ++i) {
            for (int j = 0; j < i; ++j) {
                double sum = C[i][j];
                for (int k2 = 0; k2 < j; ++k2) sum -= C[i][k2]*C[j][k2];
                C[i][j] = sum / C[j][j];
            }
            double sum = C[i][i];
            for (int k2 = 0; k2 < i; ++k2) sum -= C[i][k2]*C[i][k2];
            C[i][i] = sqrt(fmax(sum, 1e-30));
        }
        // X[:,d] = G^{-1} * Pm[d,:]^T  (forward substitution)
        double X[9][9];
        for (int d = 0; d < 9; ++d) {
            for (int e = 0; e < 9; ++e) {
                double sum = Pm[d][e];
                for (int k2 = 0; k2 < e; ++k2) sum -= C[e][k2]*X[k2][d];
                X[e][d] = sum / C[e][e];
            }
        }
        // A = All - X^T X + alpha I
        double A[9][9];
        for (int d = 0; d < 9; ++d)
            for (int g = d; g < 9; ++g) {
                double w = 0.0;
                for (int e = 0; e < 9; ++e) w += X[e][d]*X[e][g];
                double v = All[d][g] - w;
                A[d][g] = v; A[g][d] = v;
            }
        for (int d = 0; d < 9; ++d) A[d][d] += 1e-3;
        // Cholesky of A, accumulate log(diag + 1e-8)
        for (int i = 0; i < 9; ++i) {
            for (int j = 0; j < i; ++j) {
                double sum = A[i][j];
                for (int k2 = 0; k2 < j; ++k2) sum -= A[i][k2]*A[j][k2];
                A[i][j] = sum / A[j][j];
            }
            double sum = A[i][i];
            for (int k2 = 0; k2 < i; ++k2) sum -= A[i][k2]*A[i][k2];
            A[i][i] = sqrt(fmax(sum, 0.0));
            r += log(A[i][i] + 1e-8);
        }
    }
    __shared__ double red[128];
    red[t] = r;
    __syncthreads();
    for (int s = 64; s > 0; s >>= 1) {
        if (t < s) red[t] += red[t+s];
        __syncthreads();
    }
    // total = sum_{n,c} r / (NB * HALF_D) = sum r / 36
    if (t == 0) out[0] = (float)(red[0] / 36.0);
}

extern "C" void kernel_launch(void* const* d_in, const int* in_sizes, int n_in,
                              void* d_out, int out_size, void* d_ws, size_t ws_size,
                              hipStream_t stream) {
    const float* cls  = (const float*)d_in[0];   // cls_score (4,26,512,512)
    const float* tgt  = (const float*)d_in[1];   // new_targets (4,26,512,512)
    const float* mask = (const float*)d_in[2];   // valid_indices (4,512,512)

    float* ws    = (float*)d_ws;
    float* poolL = ws;
    float* poolP = poolL + (size_t)NCT * PHH * PWW;
    float* covL  = poolP + (size_t)NCT * PHH * PWW;
    float* covP  = covL  + (size_t)NCT * 45;
    float* covLP = covP  + (size_t)NCT * 45;
    float* sumL  = covLP + (size_t)NCT * 81;
    float* sumP  = sumL  + (size_t)NCT * 9;

    const int total = NCT * PHH * PWW;
    pool_kernel<<<(total + 255) / 256, 256, 0, stream>>>(cls, tgt, mask, poolL, poolP);

    dim3 gcov(NCT, 3);
    cov_kernel<<<gcov, 256, 0, stream>>>(poolL, poolP, covL, covP, covLP, sumL, sumP);

    solve_kernel<<<1, 128, 0, stream>>>(covL, covP, covLP, sumL, sumP, (float*)d_out);
}

// Round 2
// 359.543 us; speedup vs baseline: 1.1176x; 1.1176x over previous
//
#include <hip/hip_runtime.h>
#include <math.h>

#define NUM_CLASSES 26
#define HH 512
#define WW 512
#define NB 4
#define PHH 171
#define PWW 171
#define NHH 169
#define NWW 169
#define MPTS (NHH*NWW)        // 28561
#define NCT (NB*NUM_CLASSES)  // 104
#define CLIPV 1e-6f
#define NCHUNK 8
#define CHUNK ((MPTS + NCHUNK - 1) / NCHUNK)   // 3571
#define PSTRIDE 189           // 45 covL + 45 covP + 81 covLP + 9 sumL + 9 sumP

// ---------------- Kernel 1: fused mask/sigmoid + 3x3 stride-3 maxpool ----------------
// One block per (output row ph, nc). Coalesced float4 loads -> LDS -> 3x3 max.
__global__ __launch_bounds__(256) void pool_kernel(const float* __restrict__ cls,
        const float* __restrict__ tgt, const float* __restrict__ mask,
        float* __restrict__ poolL, float* __restrict__ poolP) {
    const int ph = blockIdx.x;
    const int nc = blockIdx.y;
    const int n  = nc / NUM_CLASSES;
    const int tid = threadIdx.x;

    __shared__ float Lv[3][WW];
    __shared__ float Pv[3][WW];

    for (int i = tid; i < 3 * WW; i += 256) {
        ((float*)Lv)[i] = -INFINITY;
        ((float*)Pv)[i] = -INFINITY;
    }
    __syncthreads();

    const int r0 = 3 * ph - 1;
    const float4* cls4 = (const float4*)(cls + (size_t)nc * HH * WW);
    const float4* tgt4 = (const float4*)(tgt + (size_t)nc * HH * WW);
    const float4* msk4 = (const float4*)(mask + (size_t)n  * HH * WW);

    // 3 rows x 128 float4 segments per array
    for (int i = tid; i < 3 * (WW / 4); i += 256) {
        int s   = i >> 7;       // row slot 0..2
        int seg = i & 127;
        int r = r0 + s;
        if (r < 0 || r >= HH) continue;
        float4 c4 = cls4[r * (WW / 4) + seg];
        float4 t4 = tgt4[r * (WW / 4) + seg];
        float4 m4 = msk4[r * (WW / 4) + seg];
        float cx[4] = {c4.x, c4.y, c4.z, c4.w};
        float tx[4] = {t4.x, t4.y, t4.z, t4.w};
        float mx[4] = {m4.x, m4.y, m4.z, m4.w};
        int col = seg * 4;
        #pragma unroll
        for (int k = 0; k < 4; ++k) {
            float sg = __fdividef(1.0f, 1.0f + __expf(-cx[k]));
            Pv[s][col + k] = sg * mx[k] + CLIPV;
            Lv[s][col + k] = tx[k] * mx[k];
        }
    }
    __syncthreads();

    if (tid < PWW) {
        int c0 = 3 * tid - 1;
        float mL = -INFINITY, mP = -INFINITY;
        #pragma unroll
        for (int s = 0; s < 3; ++s) {
            #pragma unroll
            for (int dc = 0; dc < 3; ++dc) {
                int c = c0 + dc;
                if (c < 0 || c >= WW) continue;
                mL = fmaxf(mL, Lv[s][c]);
                mP = fmaxf(mP, Pv[s][c]);
            }
        }
        size_t o = ((size_t)nc * PHH + ph) * PWW + tid;
        poolL[o] = mL;
        poolP[o] = mP;
    }
}

// ---------------- Kernel 2: covariance raw-sum partials ----------------
// grid (NCT, 3 modes, NCHUNK). Partial sums to ws; summed in solve_kernel.
__global__ __launch_bounds__(256) void cov_kernel(const float* __restrict__ poolL,
        const float* __restrict__ poolP, float* __restrict__ partial) {
    const int nc = blockIdx.x;
    const int mode = blockIdx.y;
    const int ch = blockIdx.z;
    const int tid = threadIdx.x;
    const int lane = tid & 63, wave = tid >> 6;
    const int pstart = ch * CHUNK;
    const int pend = (pstart + CHUNK < MPTS) ? pstart + CHUNK : MPTS;
    const float* Lb = poolL + (size_t)nc * PHH * PWW;
    const float* Pb = poolP + (size_t)nc * PHH * PWW;
    float* out = partial + ((size_t)ch * NCT + nc) * PSTRIDE;

    __shared__ float red[4][81];

    if (mode < 2) {
        const float* src = (mode == 0) ? Lb : Pb;
        float acc[45];
        float s[9];
        #pragma unroll
        for (int k = 0; k < 45; ++k) acc[k] = 0.f;
        #pragma unroll
        for (int k = 0; k < 9; ++k) s[k] = 0.f;

        for (int p = pstart + tid; p < pend; p += 256) {
            int i = p / NWW, j = p - i * NWW;
            float v[9];
            #pragma unroll
            for (int dy = 0; dy < 3; ++dy)
                #pragma unroll
                for (int dx = 0; dx < 3; ++dx)
                    v[dy * 3 + dx] = src[(i + dy) * PWW + (j + dx)];
            #pragma unroll
            for (int d = 0; d < 9; ++d) s[d] += v[d];
            int k = 0;
            #pragma unroll
            for (int d = 0; d < 9; ++d)
                #pragma unroll
                for (int e = d; e < 9; ++e)
                    acc[k++] += v[d] * v[e];
        }
        #pragma unroll
        for (int k = 0; k < 45; ++k) {
            float x = acc[k];
            #pragma unroll
            for (int off = 32; off > 0; off >>= 1) x += __shfl_down(x, off);
            if (lane == 0) red[wave][k] = x;
        }
        #pragma unroll
        for (int k = 0; k < 9; ++k) {
            float x = s[k];
            #pragma unroll
            for (int off = 32; off > 0; off >>= 1) x += __shfl_down(x, off);
            if (lane == 0) red[wave][45 + k] = x;
        }
        __syncthreads();
        if (tid < 54) {
            float x = red[0][tid] + red[1][tid] + red[2][tid] + red[3][tid];
            if (tid < 45) out[(mode == 0 ? 0 : 45) + tid] = x;
            else          out[(mode == 0 ? 171 : 180) + (tid - 45)] = x;
        }
    } else {
        float acc[81];
        #pragma unroll
        for (int k = 0; k < 81; ++k) acc[k] = 0.f;
        for (int p = pstart + tid; p < pend; p += 256) {
            int i = p / NWW, j = p - i * NWW;
            float vl[9], vp[9];
            #pragma unroll
            for (int dy = 0; dy < 3; ++dy)
                #pragma unroll
                for (int dx = 0; dx < 3; ++dx) {
                    vl[dy * 3 + dx] = Lb[(i + dy) * PWW + (j + dx)];
                    vp[dy * 3 + dx] = Pb[(i + dy) * PWW + (j + dx)];
                }
            #pragma unroll
            for (int d = 0; d < 9; ++d)
                #pragma unroll
                for (int e = 0; e < 9; ++e)
                    acc[d * 9 + e] += vl[d] * vp[e];
        }
        #pragma unroll
        for (int k = 0; k < 81; ++k) {
            float x = acc[k];
            #pragma unroll
            for (int off = 32; off > 0; off >>= 1) x += __shfl_down(x, off);
            if (lane == 0) red[wave][k] = x;
        }
        __syncthreads();
        if (tid < 81) {
            out[90 + tid] = red[0][tid] + red[1][tid] + red[2][tid] + red[3][tid];
        }
    }
}

// ---------------- Kernel 3: chunk-sum + per-(n,c) 9x9 algebra + reduction ----------------
__global__ __launch_bounds__(128) void solve_kernel(const float* __restrict__ partial,
                                                    float* __restrict__ out) {
    int t = threadIdx.x;
    double r = 0.0;
    if (t < NCT) {
        double cl[45], cp[45], clp[81], sL[9], sP[9];
        for (int k = 0; k < 45; ++k) { cl[k] = 0.0; cp[k] = 0.0; }
        for (int k = 0; k < 81; ++k) clp[k] = 0.0;
        for (int k = 0; k < 9; ++k)  { sL[k] = 0.0; sP[k] = 0.0; }
        for (int ch = 0; ch < NCHUNK; ++ch) {
            const float* q = partial + ((size_t)ch * NCT + t) * PSTRIDE;
            for (int k = 0; k < 45; ++k) { cl[k] += q[k]; cp[k] += q[45 + k]; }
            for (int k = 0; k < 81; ++k) clp[k] += q[90 + k];
            for (int k = 0; k < 9; ++k)  { sL[k] += q[171 + k]; sP[k] += q[180 + k]; }
        }
        const double M = (double)MPTS;
        double All[9][9], C[9][9], Pm[9][9];
        {
            int k = 0;
            for (int d = 0; d < 9; ++d)
                for (int e = d; e < 9; ++e) {
                    double v = cl[k] - sL[d] * sL[e] / M;
                    All[d][e] = v; All[e][d] = v;
                    double w = cp[k] - sP[d] * sP[e] / M;
                    C[d][e] = w; C[e][d] = w;
                    ++k;
                }
            for (int d = 0; d < 9; ++d)
                for (int e = 0; e < 9; ++e)
                    Pm[d][e] = clp[d * 9 + e] - sL[d] * sP[e] / M;
            for (int d = 0; d < 9; ++d) C[d][d] += 1e-3;
        }
        // Cholesky of C -> lower G (in place)
        for (int i = 0; i < 9; ++i) {
            for (int j = 0; j < i; ++j) {
                double sum = C[i][j];
                for (int k2 = 0; k2 < j; ++k2) sum -= C[i][k2] * C[j][k2];
                C[i][j] = sum / C[j][j];
            }
            double sum = C[i][i];
            for (int k2 = 0; k2 < i; ++k2) sum -= C[i][k2] * C[i][k2];
            C[i][i] = sqrt(fmax(sum, 1e-30));
        }
        // X[:,d] = G^{-1} * Pm[d,:]^T
        double X[9][9];
        for (int d = 0; d < 9; ++d) {
            for (int e = 0; e < 9; ++e) {
                double sum = Pm[d][e];
                for (int k2 = 0; k2 < e; ++k2) sum -= C[e][k2] * X[k2][d];
                X[e][d] = sum / C[e][e];
            }
        }
        // A = All - X^T X + alpha I
        double A[9][9];
        for (int d = 0; d < 9; ++d)
            for (int g = d; g < 9; ++g) {
                double w = 0.0;
                for (int e = 0; e < 9; ++e) w += X[e][d] * X[e][g];
                double v = All[d][g] - w;
                A[d][g] = v; A[g][d] = v;
            }
        for (int d = 0; d < 9; ++d) A[d][d] += 1e-3;
        // Cholesky of A, accumulate log(diag + 1e-8)
        for (int i = 0; i < 9; ++i) {
            for (int j = 0; j < i; ++j) {
                double sum = A[i][j];
                for (int k2 = 0; k2 < j; ++k2) sum -= A[i][k2] * A[j][k2];
                A[i][j] = sum / A[j][j];
            }
            double sum = A[i][i];
            for (int k2 = 0; k2 < i; ++k2) sum -= A[i][k2] * A[i][k2];
            A[i][i] = sqrt(fmax(sum, 0.0));
            r += log(A[i][i] + 1e-8);
        }
    }
    __shared__ double red[128];
    red[t] = r;
    __syncthreads();
    for (int s = 64; s > 0; s >>= 1) {
        if (t < s) red[t] += red[t + s];
        __syncthreads();
    }
    if (t == 0) out[0] = (float)(red[0] / 36.0);   // mean over n (4) and /HALF_D (9)
}

extern "C" void kernel_launch(void* const* d_in, const int* in_sizes, int n_in,
                              void* d_out, int out_size, void* d_ws, size_t ws_size,
                              hipStream_t stream) {
    const float* cls  = (const float*)d_in[0];
    const float* tgt  = (const float*)d_in[1];
    const float* mask = (const float*)d_in[2];

    float* ws      = (float*)d_ws;
    float* poolL   = ws;
    float* poolP   = poolL + (size_t)NCT * PHH * PWW;
    float* partial = poolP + (size_t)NCT * PHH * PWW;

    dim3 gpool(PHH, NCT);
    pool_kernel<<<gpool, 256, 0, stream>>>(cls, tgt, mask, poolL, poolP);

    dim3 gcov(NCT, 3, NCHUNK);
    cov_kernel<<<gcov, 256, 0, stream>>>(poolL, poolP, partial);

    solve_kernel<<<1, 128, 0, stream>>>(partial, (float*)d_out);
}